// Round 2
// baseline (2181.695 us; speedup 1.0000x reference)
//
#include <hip/hip_runtime.h>

#define SL 256
#define BATCH 8
#define NT 1024
#define LDSF 33152                    // packed triangle (floats), 16B-aligned rows
#define SCRF (7 * 1056)               // 7 blocks x [32][33] padded scratch
#define LDSB ((LDSF + 32 + SCRF) * 4) // 162,304 B dynamic LDS

// Row j (j in [1,255], holding cells (k,j), k=0..j-1) packed: rows j and 256-j
// share a 260-float slot; every row base is 16B-aligned.
__device__ __forceinline__ int roff(int j) {
  int jp = (j > 128) ? (256 - j) : j;
  int base = (jp - 1) * 260;
  if (j > 128) base += (jp + 3) & ~3;
  return base;
}

__global__ __launch_bounds__(NT) void cyk_blk(
    const float* __restrict__ scores, float* __restrict__ out,
    float* __restrict__ ws) {
  extern __shared__ float sh[];
  float* red = sh + LDSF;          // 32 floats
  float* scr = sh + LDSF + 32;     // 7 * 1056 floats
  const int b = blockIdx.x;
  const int tid = threadIdx.x;
  const int lane = tid & 63;
  const int wv = tid >> 6;         // 16 waves
  const int c = lane >> 1;         // cell index within wave (2 lanes/cell)
  const int hi = lane & 1;
  const size_t P = (size_t)SL * SL;
  const float* sc = scores + (size_t)b * P;
  float* g   = out + (size_t)b * P;
  float* Hg  = ws + (size_t)b * P;               // H row-major
  float* HTg = ws + (size_t)(BATCH + b) * P;     // H transposed

  // ---- init: zero triangle + red ----
  for (int idx = tid * 4; idx < LDSF; idx += NT * 4)
    *(float4*)(sh + idx) = make_float4(0.f, 0.f, 0.f, 0.f);
  if (tid < 32) red[tid] = 0.f;
  __syncthreads();

  // width-1 seeds for in-diag-block cells (log space)
  for (int i = tid; i < SL - 1; i += NT)
    if ((i & 31) != 31) sh[roff(i + 1) + i] = sc[i * SL + i + 1];
  __syncthreads();

  // ---- A) diagonal blocks, widths 2..31, log space, one wave per block ----
  if (wv < 8) {
    const int Rb = wv << 5;
    for (int w2 = 2; w2 <= 31; ++w2) {
      asm volatile("s_waitcnt lgkmcnt(0)" ::: "memory");
      const bool val = c < 32 - w2;
      const int i = Rb + c, j = i + w2;
      const float scv = val ? sc[i * SL + j] : 0.f;
      const int oj = roff(j);
      float m = -1e30f, sm = 0.f;
      if (val) {
        for (int t = hi; t < w2 - 1; t += 2) {
          int k = i + 1 + t;
          float tv = sh[roff(k) + i] + sh[oj + k];
          float nm = fmaxf(m, tv);
          sm = sm * __expf(m - nm) + __expf(tv - nm);
          m = nm;
        }
      }
      float mo = __shfl_xor(m, 1, 64), so = __shfl_xor(sm, 1, 64);
      float nm = fmaxf(m, mo);
      sm = sm * __expf(m - nm) + so * __expf(mo - nm);
      m = nm;
      if (val && hi == 0) sh[oj + i] = scv + m + __logf(sm);
    }
  }
  __syncthreads();

  // ---- B) calibrate cc from width-31 cells; convert diag blocks to E-space ----
  if (tid < 8) { int Rb = tid << 5; red[tid] = sh[roff(Rb + 31) + Rb]; }
  __syncthreads();
  float cc = red[0];
#pragma unroll
  for (int t = 1; t < 8; ++t) cc = fmaxf(cc, red[t]);
  cc *= (1.f / 31.f);
  const float eNegCc = __expf(-cc);
  __syncthreads();
  for (int idx = tid; idx < 8 * 1024; idx += NT) {
    int bb = idx >> 10, r = (idx >> 5) & 31, q = idx & 31;
    if (q > r) {
      int i = (bb << 5) + r, j = (bb << 5) + q;
      int o = roff(j) + i;
      sh[o] = __expf(sh[o] - cc * (float)(q - r));
    }
  }
  __syncthreads();

  // ---- C) inside: block anti-diagonals d = 1..7 ----
  for (int d = 1; d <= 7; ++d) {
    const int nblk = 8 - d;
    // C1: mid GEMM over interior k-blocks (dense, all threads)
    if (d >= 2) {
      for (int bb = 0; bb < nblk; ++bb) {
        const int Ri = bb << 5, Cj = (bb + d) << 5;
        const int i = Ri + (tid & 31), j = Cj + (tid >> 5);
        const int oj = roff(j);
        float acc = 0.f;
#pragma unroll 4
        for (int k = Ri + 32; k < Cj; ++k)
          acc = fmaf(sh[roff(k) + i], sh[oj + k], acc);
        sh[oj + i] = acc;   // S_mid staged in the cell slot
      }
      __syncthreads();
    }
    // C2: in-block serial micro-steps, one wave per block, no barriers
    float wmax = 0.f;
    if (wv < nblk) {
      const int Ri = wv << 5, Cj = (wv + d) << 5;
      for (int u = 0; u <= 62; ++u) {
        const int cmin = (u > 31) ? (u - 31) : 0;
        const int cmax = (u < 31) ? u : 31;
        const bool val = (c >= cmin) && (c <= cmax);
        const int a = c;
        const int j = Cj + a, i = Ri + 31 - u + a;
        const int oj = roff(j);
        const float scv = val ? sc[i * SL + j] : 0.f;  // issued early
        asm volatile("s_waitcnt lgkmcnt(0)" ::: "memory");
        const float smid = val ? sh[oj + i] : 0.f;
        float a0 = 0.f, a1 = 0.f;
        if (val) {
          const int bt = u - a;        // # right-edge terms (k in diag bi)
#pragma unroll 4
          for (int t = hi; t < u; t += 2) {
            int k = (t < bt) ? (i + 1 + t) : (Cj + t - bt);
            float e1 = sh[roff(k) + i];
            float e2 = sh[oj + k];
            if (hi) a1 = fmaf(e1, e2, a1); else a0 = fmaf(e1, e2, a0);
          }
        }
        float acc = a0 + a1;
        acc += __shfl_xor(acc, 1, 64);
        if (val && hi == 0) {
          float tot = smid + acc + ((d == 1 && u == 0) ? eNegCc : 0.f);
          wmax = fmaxf(wmax, tot);
          sh[oj + i] = __expf(scv) * tot;
        }
      }
    }
#pragma unroll
    for (int o = 32; o; o >>= 1) wmax = fmaxf(wmax, __shfl_xor(wmax, o, 64));
    if (wv < nblk && lane == 0) red[8 + wv] = wmax;
    __syncthreads();
    // C3: drift check + exact rescale sweep (uniform)
    float mx = red[8];
    for (int t = 1; t < nblk; ++t) mx = fmaxf(mx, red[8 + t]);
    if (mx > 1e10f || mx < 1e-12f) {
      const float dc = (__logf(fmaxf(mx, 1e-30f)) + 8.0f) / (float)(32 * d + 31);
      const int wcur = 32 * d + 31;
      for (int j = 1 + wv; j < SL; j += 16) {
        int jlo = j - wcur; if (jlo < 0) jlo = 0;
        int base = roff(j);
        for (int i2 = jlo + lane; i2 < j; i2 += 64)
          sh[base + i2] *= __expf(-dc * (float)(j - i2));
      }
      __syncthreads();
    }
  }

  // ---- D) root ----
  if (tid == 0) {
    float Er = sh[roff(SL - 1) + 0];
    red[20] = (Er > 0.f) ? __expf(sc[SL - 1]) / Er : 0.f;
  }
  __syncthreads();
  const float Hr = red[20];

  // ---- E) outside: block anti-diagonals d = 7..1 ----
  for (int d = 7; d >= 1; --d) {
    const int nblk = 8 - d;
    // E1: mid gathers from finalized H (global) x E (LDS), into scratch
    for (int bb = 0; bb < nblk; ++bb) {
      const int Rp = bb << 5, Cq = (bb + d) << 5;
      const int pg = tid >> 5, qi = tid & 31;
      const int p = Rp + pg, q = Cq + qi;
      const int op = roff(p);       // unused when Rp==0 (loop empty)
      float acc = 0.f;
#pragma unroll 4
      for (int j = Cq + 32; j < SL; ++j)
        acc = fmaf(sh[roff(j) + q], HTg[j * SL + p], acc);
#pragma unroll 4
      for (int i = 0; i < Rp; ++i)
        acc = fmaf(sh[op + i], Hg[i * SL + q], acc);
      if (d == 7 && bb == 0 && pg == 0 && qi == 31) acc = Hr;  // root seed
      scr[bb * 1056 + pg * 33 + qi] = acc;
    }
    __syncthreads();
    // E2: in-block serial micro-steps (H in scratch, E in LDS triangle)
    if (wv < nblk) {
      const int Rp = wv << 5, Cq = (wv + d) << 5;
      float* S = scr + wv * 1056;
      for (int u = 0; u <= 62; ++u) {
        const int cmin = (u > 31) ? (u - 31) : 0;
        const int cmax = (u < 31) ? u : 31;
        const int a = c;
        const bool val = (c >= cmin) && (c <= cmax) && !(d == 7 && u == 0);
        const int q = Cq + 31 - a, p = Rp + u - a;
        const float scv = val ? sc[p * SL + q] : 0.f;
        asm volatile("s_waitcnt lgkmcnt(0)" ::: "memory");
        const float smid = val ? S[(u - a) * 33 + (31 - a)] : 0.f;
        float a0 = 0.f, a1 = 0.f;
        if (val) {
          const int bt = u - a;        // # up-edge terms (i in [Rp,p))
          const int op2 = roff(p);
#pragma unroll 4
          for (int t = hi; t < u; t += 2) {
            float e, h;
            if (t < bt) {
              int i2 = Rp + t;
              e = sh[op2 + i2];
              h = S[t * 33 + (31 - a)];
            } else {
              int j2 = q + 1 + (t - bt);
              e = sh[roff(j2) + q];
              h = S[bt * 33 + (j2 - Cq)];
            }
            if (hi) a1 = fmaf(e, h, a1); else a0 = fmaf(e, h, a0);
          }
        }
        float acc = a0 + a1;
        acc += __shfl_xor(acc, 1, 64);
        if (val && hi == 0)
          S[(u - a) * 33 + (31 - a)] = __expf(scv) * (smid + acc);
      }
    }
    __syncthreads();
    // E3: post — g + Hg (p-major, coalesced) and HTg (q-major, coalesced)
    for (int bb = 0; bb < nblk; ++bb) {
      const int Rp = bb << 5, Cq = (bb + d) << 5;
      const float* S = scr + bb * 1056;
      {
        const int pg = tid >> 5, qi = tid & 31;
        const int p = Rp + pg, q = Cq + qi;
        float H = S[pg * 33 + qi];
        Hg[p * SL + q] = H;
        g[p * SL + q] = sh[roff(q) + p] * H * __expf(-sc[p * SL + q]);
      }
      {
        const int qg = tid >> 5, pi = tid & 31;
        const int p = Rp + pi, q = Cq + qg;
        HTg[q * SL + p] = S[pi * 33 + qg];
      }
    }
    __syncthreads();
  }

  // ---- F) outside diagonal blocks (d=0), two sub-rounds of 4 blocks ----
  for (int sr = 0; sr < 2; ++sr) {
    for (int bb = 0; bb < 4; ++bb) {          // F1: mid
      const int Rb = (sr * 4 + bb) << 5;
      const int pg = tid >> 5, qi = tid & 31;
      const int p = Rb + pg, q = Rb + qi;
      const int op = roff(p);                 // unused when Rb==0,pg==0
      float acc = 0.f;
#pragma unroll 4
      for (int j = Rb + 32; j < SL; ++j)
        acc = fmaf(sh[roff(j) + q], HTg[j * SL + p], acc);
#pragma unroll 4
      for (int i = 0; i < Rb; ++i)
        acc = fmaf(sh[op + i], Hg[i * SL + q], acc);
      scr[bb * 1056 + pg * 33 + qi] = acc;
    }
    __syncthreads();
    if (wv < 4) {                              // F2: micro (31 steps)
      const int Rb = (sr * 4 + wv) << 5;
      float* S = scr + wv * 1056;
      for (int u = 0; u <= 30; ++u) {
        const int a = c;
        const bool val = (c <= u);
        const int q = Rb + 31 - a, p = Rb + u - a;
        const float scv = val ? sc[p * SL + q] : 0.f;
        asm volatile("s_waitcnt lgkmcnt(0)" ::: "memory");
        const float smid = val ? S[(u - a) * 33 + (31 - a)] : 0.f;
        float a0 = 0.f, a1 = 0.f;
        if (val) {
          const int bt = u - a;
          const int op2 = roff(p);
#pragma unroll 4
          for (int t = hi; t < u; t += 2) {
            float e, h;
            if (t < bt) {
              int i2 = Rb + t;
              e = sh[op2 + i2];
              h = S[t * 33 + (31 - a)];
            } else {
              int j2 = q + 1 + (t - bt);
              e = sh[roff(j2) + q];
              h = S[bt * 33 + (j2 - Rb)];
            }
            if (hi) a1 = fmaf(e, h, a1); else a0 = fmaf(e, h, a0);
          }
        }
        float acc = a0 + a1;
        acc += __shfl_xor(acc, 1, 64);
        if (val && hi == 0)
          S[(u - a) * 33 + (31 - a)] = __expf(scv) * (smid + acc);
      }
    }
    __syncthreads();
    for (int bb = 0; bb < 4; ++bb) {           // F3: g only (upper tri)
      const int Rb = (sr * 4 + bb) << 5;
      const float* S = scr + bb * 1056;
      const int pg = tid >> 5, qi = tid & 31;
      if (qi > pg) {
        const int p = Rb + pg, q = Rb + qi;
        g[p * SL + q] = sh[roff(q) + p] * S[pg * 33 + qi] * __expf(-sc[p * SL + q]);
      }
    }
    __syncthreads();
  }
}

// ---------------- fallback: v2 global-memory kernel (proven) ----------------
__device__ __forceinline__ float grpMaxR(float v, int G) {
#pragma unroll
  for (int o = 32; o; o >>= 1)
    if (o < G) v = fmaxf(v, __shfl_xor(v, o, 64));
  return v;
}
__device__ __forceinline__ float grpSumR(float v, int G) {
#pragma unroll
  for (int o = 32; o; o >>= 1)
    if (o < G) v += __shfl_xor(v, o, 64);
  return v;
}

__global__ __launch_bounds__(NT) void cyk_io_fb(
    const float* __restrict__ scores, float* __restrict__ out,
    float* __restrict__ ws) {
  const int b = blockIdx.x;
  const int tid = threadIdx.x;
  const size_t P = (size_t)SL * SL;
  const float* sc = scores + (size_t)b * P;
  float* g = out + (size_t)b * P;
  float* s = ws + (size_t)b * P;
  float* l = ws + (size_t)(BATCH + b) * P;

  for (int i = tid; i < SL - 1; i += NT) {
    s[i * SL + i + 1] = sc[i * SL + i + 1];
    l[i * SL + i + 1] = 0.f;
  }
  __syncthreads();

  for (int w = 2; w < SL; ++w) {
    const int cells = SL - w;
    int G = NT / cells;
    G = (G >= 64) ? 64 : (1 << (31 - __clz(G)));
    const int lg = 31 - __clz(G);
    const int c = tid >> lg;
    const int lig = tid & (G - 1);
    if (c < cells) {
      const int i = c, j = i + w;
      const float* srow = s + i * SL;
      float m = -INFINITY;
      for (int k = i + 1 + lig; k < j; k += G)
        m = fmaxf(m, srow[k] + s[k * SL + j]);
      m = grpMaxR(m, G);
      float sum = 0.f;
      for (int k = i + 1 + lig; k < j; k += G)
        sum += __expf(srow[k] + s[k * SL + j] - m);
      sum = grpSumR(sum, G);
      if (lig == 0) {
        const float lse = m + __logf(sum);
        s[i * SL + j] = sc[i * SL + j] + lse;
        l[i * SL + j] = lse;
      }
    }
    __syncthreads();
  }

  if (tid == 0) g[0 * SL + (SL - 1)] = 1.0f;
  __syncthreads();

  for (int w = SL - 2; w >= 1; --w) {
    const int cells = SL - w;
    int G = NT / cells;
    G = (G >= 64) ? 64 : (1 << (31 - __clz(G)));
    const int lg = 31 - __clz(G);
    const int c = tid >> lg;
    const int lig = tid & (G - 1);
    if (c < cells) {
      const int p = c, q = p + w;
      const float spq = s[p * SL + q];
      const int TR = SL - 1 - q;
      const int T = TR + p;
      float acc = 0.f;
      for (int t = lig; t < T; t += G) {
        if (t < TR) {
          const int j = q + 1 + t;
          acc += g[p * SL + j] * __expf(spq + s[q * SL + j] - l[p * SL + j]);
        } else {
          const int i = t - TR;
          acc += g[i * SL + q] * __expf(s[i * SL + p] + spq - l[i * SL + q]);
        }
      }
      acc = grpSumR(acc, G);
      if (lig == 0) g[p * SL + q] = acc;
    }
    __syncthreads();
  }
}

extern "C" void kernel_launch(void* const* d_in, const int* in_sizes, int n_in,
                              void* d_out, int out_size, void* d_ws, size_t ws_size,
                              hipStream_t stream) {
  const float* scores = (const float*)d_in[0];
  // d_in[1] = mask: triu(k=1) broadcast -> lens == SL-1 always; unused.
  float* out = (float*)d_out;
  float* ws = (float*)d_ws;

  const size_t sq = (size_t)SL * SL * sizeof(float);       // 256 KB
  hipMemsetAsync(d_out, 0, (size_t)BATCH * sq, stream);

  int dev = 0;
  hipGetDevice(&dev);
  int maxShm = 0;
  hipDeviceGetAttribute(&maxShm, hipDeviceAttributeMaxSharedMemoryPerBlock, dev);
  (void)hipFuncSetAttribute(reinterpret_cast<const void*>(cyk_blk),
                            hipFuncAttributeMaxDynamicSharedMemorySize, LDSB);

  if (maxShm >= LDSB && ws_size >= (size_t)2 * BATCH * sq) {
    hipMemsetAsync(ws, 0, (size_t)2 * BATCH * sq, stream);  // Hg/HTg guards = 0
    cyk_blk<<<BATCH, NT, LDSB, stream>>>(scores, out, ws);
  } else {
    cyk_io_fb<<<BATCH, NT, 0, stream>>>(scores, out, ws);
  }
}

// Round 4
// 703.801 us; speedup vs baseline: 3.0999x; 3.0999x over previous
//
#include <hip/hip_runtime.h>

#define SL 256
#define BATCH 8
#define NT 1024
#define W0 16
#define LDSF 33152                          // packed triangle (floats), 16B-aligned rows
#define TABN 264                            // 256 + zero pad (paranoia)
#define LDSB ((LDSF + 32 + TABN + 256) * 4) // red(32) + tab + E1(256) = 134,816 B

// Row j (j in [1,255], holding cells (k,j), k=0..j-1) packed: rows j and 256-j
// share a 260-float slot; every row base is 16B-aligned.
__device__ __forceinline__ int rowOff(int j) {
  int jp = (j > 128) ? (256 - j) : j;
  int base = (jp - 1) * 260;
  if (j > 128) base += (jp + 3) & ~3;
  return base;
}

template <int G>
__device__ __forceinline__ float grpSum(float v) {
#pragma unroll
  for (int o = G >> 1; o; o >>= 1) v += __shfl_xor(v, o, 64);
  return v;
}

// Raw barrier draining only LDS ops: global stores (g output) float across it.
__device__ __forceinline__ void barrier_lgkm() {
  __builtin_amdgcn_sched_barrier(0);
  asm volatile("s_waitcnt lgkmcnt(0)" ::: "memory");
  __builtin_amdgcn_s_barrier();
  __builtin_amdgcn_sched_barrier(0);
}

// Rescale LDS E triangle (+E1 copy) by exp(-dc*width) for widths <= wcur.
__device__ void rescaleE(int tid, float dc, int wcur, float* sh, float* E1,
                         const int* __restrict__ tab) {
  const int lane = tid & 63, wave = tid >> 6;
  for (int j = 1 + wave; j < SL; j += 16) {
    int jlo = j - wcur; if (jlo < 0) jlo = 0;
    int base = tab[j];
    for (int i = jlo + lane; i < j; i += 64)
      sh[base + i] *= __expf(-dc * (float)(j - i));
  }
  const float f1 = __expf(-dc);
  for (int i = tid; i < SL - 1; i += NT) E1[i] *= f1;
}

// ---- paired inside: one barrier computes widths (w, w+1) ----
// Wave-local row mapping: i = wv*(NG-1) + l, 1-row overlap between waves so the
// w+1 fixup's neighbor (row i+1 width-w value) is always in-wave via shfl_down.
// RANGE masks (two-sided) keep every tail/garbage read dead: boundary rows are
// computed by two waves, and the twin may have already written this step's
// cells — one-sided masks raced on E[i,j]/E[i,j+1] tails (round-3 bug).
template <int G>
__device__ void insideP(int wlo, int whi, int tid, const float* __restrict__ sc,
                        float* __restrict__ sh, float* __restrict__ red,
                        const int* __restrict__ tab, float* __restrict__ E1) {
  constexpr int LG = (G == 4) ? 2 : (G == 8) ? 3 : (G == 16) ? 4 : 5;
  constexpr int NG = 64 / G;
  const int lane = tid & 63, wv = tid >> 6;
  const int l = lane >> LG, lig = lane & (G - 1);
  const int i = wv * (NG - 1) + l;
  for (int w = wlo; w <= whi; w += 2) {
    const int t = ((w - 17) >> 1) + 1;            // global pair-step counter
    const float fl = red[16 + ((t - 1) & 1)];     // flag from previous step
    const unsigned wm1 = (unsigned)(w - 1);       // a: k-i-1 in [0, w-2]
    const unsigned wm2 = (unsigned)(w - 2);       // b: k-i-2 in [0, w-3]
    const bool vw = i < SL - w;
    const bool vw1 = (l < NG - 1) && (i < SL - w - 1);
    const int jw = (i + w < SL) ? i + w : SL - 1;
    const int jw1 = (i + w + 1 < SL) ? i + w + 1 : SL - 1;
    const int ojw = tab[jw], ojw1 = tab[jw1];
    const float scw = sc[i * SL + jw];            // all lanes (uniform per group)
    const float scw1 = sc[i * SL + jw1];
    float a0 = 0.f, a1 = 0.f, b0 = 0.f, b1 = 0.f;
    if (vw) {
      // merged bulk: shared gather E[i,k]; rows jw (k in (i,j)) and jw1
      // (k in (i+1,j)); two-sided masks kill all tails (race-proof).
      for (int s4 = ((i + 1) & ~3) + 4 * lig; s4 < i + w; s4 += 4 * G) {
        float4 rw = *(const float4*)(sh + ojw + s4);
        float4 rw1 = *(const float4*)(sh + ojw1 + s4);
        int4 tv = *(const int4*)(tab + s4);
        float e0 = sh[tv.x + i], e1 = sh[tv.y + i];
        float e2 = sh[tv.z + i], e3 = sh[tv.w + i];
        const int d0 = s4 - i;                    // k - i for element 0
        float f0 = ((unsigned)(d0 - 1) < wm1) ? e0 : 0.f;
        float f1 = ((unsigned)(d0    ) < wm1) ? e1 : 0.f;
        float f2 = ((unsigned)(d0 + 1) < wm1) ? e2 : 0.f;
        float f3 = ((unsigned)(d0 + 2) < wm1) ? e3 : 0.f;
        a0 = fmaf(f0, rw.x, a0); a1 = fmaf(f1, rw.y, a1);
        a0 = fmaf(f2, rw.z, a0); a1 = fmaf(f3, rw.w, a1);
        float g0 = ((unsigned)(d0 - 2) < wm2) ? e0 : 0.f;
        float g1 = ((unsigned)(d0 - 1) < wm2) ? e1 : 0.f;
        float g2 = ((unsigned)(d0    ) < wm2) ? e2 : 0.f;
        float g3 = ((unsigned)(d0 + 1) < wm2) ? e3 : 0.f;
        b0 = fmaf(g0, rw1.x, b0); b1 = fmaf(g1, rw1.y, b1);
        b0 = fmaf(g2, rw1.z, b0); b1 = fmaf(g3, rw1.w, b1);
      }
    }
    float accw = grpSum<G>(a0 + a1);
    float accw1 = grpSum<G>(b0 + b1);
    float Ew = __expf(scw) * accw;                // all lanes (for shfl)
    if (vw && lig == 0) {
      sh[ojw + i] = Ew;
      if (accw > 3.5e19f || accw < 3e-16f) red[16 + (t & 1)] = fmaxf(accw, 1e-30f);
    }
    float EwN = __shfl_down(Ew, G, 64);           // row i+1 width-w value
    if (vw1) {
      float tot = accw1 + E1[i] * EwN + Ew * E1[jw];
      if (lig == 0) {
        sh[ojw1 + i] = __expf(scw1) * tot;
        if (tot > 3.5e19f || tot < 3e-16f) red[16 + (t & 1)] = fmaxf(tot, 1e-30f);
      }
    }
    __syncthreads();
    if (fl != 0.f) {                              // uniform; deferred one pair
      float dc = (__logf(fl) + 8.0f) / (float)(w - 2);
      rescaleE(tid, dc, w + 1, sh, E1, tab);
      __syncthreads();
      if (tid == 0) { red[16] = 0.f; red[17] = 0.f; }
      __syncthreads();
    }
  }
}

// ---- paired outside: one barrier computes widths (wA, wB=wA-1) descending ----
template <int G>
__device__ void outsideP(int wAhi, int wAlo, int tid, const float* __restrict__ sc,
                         float* __restrict__ gOut, const float* __restrict__ Eg,
                         const float* __restrict__ ETg, float* __restrict__ shH,
                         const int* __restrict__ tab, const float* __restrict__ E1) {
  constexpr int LG = (G == 4) ? 2 : (G == 8) ? 3 : (G == 16) ? 4 : 5;
  constexpr int NG = 64 / G;
  const int lane = tid & 63, wv = tid >> 6;
  const int l = lane >> LG, lig = lane & (G - 1);
  const int p = wv * (NG - 1) + l;
  for (int wA = wAhi; wA >= wAlo; wA -= 2) {
    const int wB = wA - 1;
    const bool vA = p < SL - wA;
    const bool vB = (l >= 1 || wv == 0) && (p < SL - wB);  // dedup boundary row
    const int qA = p + wA, qB = p + wB;
    const int qAc = (qA < SL) ? qA : SL - 1;
    const int qBc = (qB < SL) ? qB : SL - 1;
    const int oA = tab[qAc], oB = tab[qBc];
    const float scA = sc[p * SL + qAc];
    const float scB = sc[p * SL + qBc];
    float EpA = 0.f, EpB = 0.f;
    if (lig == 0) {
      if (vA) EpA = Eg[p * SL + qA];
      if (vB) EpB = Eg[p * SL + qB];
    }
    float a0 = 0.f, a1 = 0.f, b0 = 0.f, b1 = 0.f;
    if (vA || vB) {
      const float* erA = Eg + (size_t)qAc * SL;
      const float* erB = Eg + (size_t)qBc * SL;
      // right parents j >= qA+1 (shared H[p,j] gather; widths > wA, stable)
      for (int s4 = ((qA + 1) & ~3) + 4 * lig; s4 < SL; s4 += 4 * G) {
        float4 eA = *(const float4*)(erA + s4);
        float4 eB = *(const float4*)(erB + s4);
        int4 tv = *(const int4*)(tab + s4);
        float h0 = shH[tv.x + p], h1 = shH[tv.y + p];
        float h2 = shH[tv.z + p], h3 = shH[tv.w + p];
        float m0 = (s4 + 0 > qA) ? h0 : 0.f, m1 = (s4 + 1 > qA) ? h1 : 0.f;
        float m2 = (s4 + 2 > qA) ? h2 : 0.f, m3 = (s4 + 3 > qA) ? h3 : 0.f;
        a0 = fmaf(eA.x, m0, a0); a1 = fmaf(eA.y, m1, a1);
        a0 = fmaf(eA.z, m2, a0); a1 = fmaf(eA.w, m3, a1);
        b0 = fmaf(eB.x, m0, b0); b1 = fmaf(eB.y, m1, b1);
        b0 = fmaf(eB.z, m2, b0); b1 = fmaf(eB.w, m3, b1);
      }
      // left parents i < p (A: all; B: i < p-1, edge i=p-1 in fixup).
      // Tail i>=p is dead via ETg zero-guard (E[i,p]=0 for i>=p).
      for (int s4 = 4 * lig; s4 < p; s4 += 4 * G) {
        float4 ev = *(const float4*)(ETg + (size_t)p * SL + s4);
        float4 hA = *(const float4*)(shH + oA + s4);
        float4 hB = *(const float4*)(shH + oB + s4);
        a0 = fmaf(ev.x, hA.x, a0); a1 = fmaf(ev.y, hA.y, a1);
        a0 = fmaf(ev.z, hA.z, a0); a1 = fmaf(ev.w, hA.w, a1);
        float n0 = (s4 + 0 < p - 1) ? hB.x : 0.f;
        float n1 = (s4 + 1 < p - 1) ? hB.y : 0.f;
        float n2 = (s4 + 2 < p - 1) ? hB.z : 0.f;
        float n3 = (s4 + 3 < p - 1) ? hB.w : 0.f;
        b0 = fmaf(ev.x, n0, b0); b1 = fmaf(ev.y, n1, b1);
        b0 = fmaf(ev.z, n2, b0); b1 = fmaf(ev.w, n3, b1);
      }
    }
    float accA = grpSum<G>(a0 + a1);
    float accBb = grpSum<G>(b0 + b1);
    float HA = __expf(scA) * accA;                // all lanes (for shfl)
    if (vA && lig == 0) {
      shH[oA + p] = HA;
      gOut[p * SL + qA] = EpA * accA;
    }
    float HAup = __shfl_up(HA, G, 64);            // row p-1 width-wA value
    if (vB) {
      float accB = accBb + (vA ? E1[qB] * HA : 0.f)
                         + ((p > 0) ? E1[p - 1] * HAup : 0.f);
      if (lig == 0) {
        shH[oB + p] = __expf(scB) * accB;
        gOut[p * SL + qB] = EpB * accB;
      }
    }
    barrier_lgkm();
  }
}

// ---- unpaired outside (proven round-1 shape) for small widths ----
template <int G>
__device__ void outsideB(int w0, int w1, int tid,
    const float* __restrict__ sc, float* __restrict__ gOut,
    const float* __restrict__ Eg, const float* __restrict__ ETg,
    float* __restrict__ shH, const int* __restrict__ tab) {
  constexpr int LG = (G == 4) ? 2 : (G == 8) ? 3 : (G == 16) ? 4 : (G == 32) ? 5 : 6;
  const int c = tid >> LG, lig = tid & (G - 1);
  for (int w = w0; w >= w1; --w) {
    if (c < SL - w) {
      const int p = c, q = p + w;
      float scv = 0.f, Epq = 0.f;
      if (lig == 0) { scv = sc[p * SL + q]; Epq = Eg[p * SL + q]; }
      float a0 = 0.f, a1 = 0.f;
      const float* er = Eg + (size_t)q * SL;
      for (int s4 = ((q + 1) & ~3) + 4 * lig; s4 < SL; s4 += 4 * G) {
        float4 ev = *(const float4*)(er + s4);
        int4 tv = *(const int4*)(tab + s4);
        float h0 = shH[tv.x + p], h1 = shH[tv.y + p];
        float h2 = shH[tv.z + p], h3 = shH[tv.w + p];
        a0 = fmaf(ev.x, (s4 + 0 > q) ? h0 : 0.f, a0);
        a1 = fmaf(ev.y, (s4 + 1 > q) ? h1 : 0.f, a1);
        a0 = fmaf(ev.z, (s4 + 2 > q) ? h2 : 0.f, a0);
        a1 = fmaf(ev.w, (s4 + 3 > q) ? h3 : 0.f, a1);
      }
      if (p > 0) {
        const float* et = ETg + (size_t)p * SL;
        const float* hq = shH + tab[q];
        for (int s4 = 4 * lig; s4 < p; s4 += 4 * G) {
          float4 ev = *(const float4*)(et + s4);   // zero for i >= p (memset guard)
          float4 hv = *(const float4*)(hq + s4);
          a0 = fmaf(ev.x, hv.x, a0);
          a1 = fmaf(ev.y, hv.y, a1);
          a0 = fmaf(ev.z, hv.z, a0);
          a1 = fmaf(ev.w, hv.w, a1);
        }
      }
      float acc = grpSum<G>(a0 + a1);
      if (lig == 0) {
        gOut[p * SL + q] = Epq * acc;
        shH[tab[q] + p] = acc * __expf(scv);
      }
    }
    barrier_lgkm();
  }
}

__global__ __launch_bounds__(NT) void cyk_pair(
    const float* __restrict__ scores, float* __restrict__ out,
    float* __restrict__ ws) {
  extern __shared__ float sh[];
  float* red = sh + LDSF;
  int* tab = (int*)(sh + LDSF + 32);
  float* E1 = sh + LDSF + 32 + TABN;
  const int b = blockIdx.x;
  const int tid = threadIdx.x;
  const int lane = tid & 63;
  const int wave = tid >> 6;
  const size_t P = (size_t)SL * SL;
  const float* sc = scores + (size_t)b * P;
  float* g   = out + (size_t)b * P;
  float* Eg  = ws + (size_t)b * P;                 // E row-major (read-only after dump)
  float* ETg = ws + (size_t)(BATCH + b) * P;       // E col-major (read-only after dump)

  for (int idx = tid * 4; idx < LDSF; idx += NT * 4)
    *(float4*)(sh + idx) = make_float4(0.f, 0.f, 0.f, 0.f);
  if (tid < 32) red[tid] = 0.f;
  if (tid < TABN) tab[tid] = (tid >= 1 && tid <= 255) ? rowOff(tid) : 0;
  __syncthreads();

  // width 1 seeds (log space)
  for (int i = tid; i < SL - 1; i += NT)
    sh[tab[i + 1] + i] = sc[i * SL + i + 1];
  __syncthreads();

  // ---- phase A: widths 2..W0, log space ----
  {
    const int c4 = tid >> 2, lig = tid & 3;
    for (int w = 2; w <= W0; ++w) {
      if (c4 < SL - w) {
        const int i = c4, j = i + w;
        const int oj = tab[j];
        float scv = 0.f;
        if (lig == 0) scv = sc[i * SL + j];
        float m = -1e30f, sum = 0.f;
        for (int k = i + 1 + lig; k < j; k += 4) {
          float t = sh[tab[k] + i] + sh[oj + k];
          float nm = fmaxf(m, t);
          sum = sum * __expf(m - nm) + __expf(t - nm);
          m = nm;
        }
#pragma unroll
        for (int o = 2; o; o >>= 1) {
          float mo = __shfl_xor(m, o, 64);
          float so = __shfl_xor(sum, o, 64);
          float nm = fmaxf(m, mo);
          sum = sum * __expf(m - nm) + so * __expf(mo - nm);
          m = nm;
        }
        if (lig == 0) sh[oj + i] = scv + m + __logf(sum);
      }
      __syncthreads();
    }
  }

  // ---- calibrate cc = max(s at width W0)/W0 ----
  {
    int idx = tid < SL - W0 ? tid : SL - W0 - 1;
    float v = sh[tab[idx + W0] + idx];
#pragma unroll
    for (int o = 32; o; o >>= 1) v = fmaxf(v, __shfl_xor(v, o, 64));
    if (lane == 0) red[wave] = v;
  }
  __syncthreads();
  float cc;
  {
    float mx = red[0];
#pragma unroll
    for (int t = 1; t < 16; ++t) mx = fmaxf(mx, red[t]);
    cc = mx / (float)W0;
  }

  // ---- convert widths 1..W0 to E-space; fill E1 ----
  for (int w = 1; w <= W0; ++w) {
    for (int i = tid; i < SL - w; i += NT) {
      int o = tab[i + w] + i;
      float E = __expf(sh[o] - cc * (float)w);
      sh[o] = E;
      if (w == 1) E1[i] = E;
    }
  }
  if (tid == 0) { red[16] = 0.f; red[17] = 0.f; }
  __syncthreads();

  // ---- inside: width pairs (one barrier per 2 widths) ----
  insideP<4>(17, 141, tid, sc, sh, red, tab, E1);
  insideP<8>(143, 205, tid, sc, sh, red, tab, E1);
  insideP<16>(207, 237, tid, sc, sh, red, tab, E1);
  insideP<32>(239, 253, tid, sc, sh, red, tab, E1);

  // ---- width 255 (single cell) ----
  {
    float acc = 0.f;
    if (wave == 0) {
      const int o255 = tab[255];
      for (int k = 1 + lane; k < 255; k += 64)
        acc += sh[tab[k]] * sh[o255 + k];          // E[0,k] * E[k,255]
#pragma unroll
      for (int o = 32; o; o >>= 1) acc += __shfl_xor(acc, o, 64);
      if (lane == 0) sh[o255] = __expf(sc[SL - 1]) * acc;
    }
    __syncthreads();
  }

  // ---- dump E -> Eg (row-major) + ETg (col-major); root ----
  for (int idx = tid; idx < SL * SL; idx += NT) {
    int j = idx >> 8, i = idx & 255;
    if (i < j) ETg[idx] = sh[tab[j] + i];
  }
  for (int idx = tid; idx < SL * SL; idx += NT) {
    int i = idx >> 8, k = idx & 255;
    if (k > i) Eg[idx] = sh[tab[k] + i];
  }
  if (tid == 0) {
    float Er = sh[tab[SL - 1]];
    red[20] = (Er > 0.f) ? __expf(sc[SL - 1]) / Er : 0.f;
    g[SL - 1] = 1.0f;
  }
  __syncthreads();                                 // drains vmcnt: E visible

  // ---- re-init LDS triangle as H; seed root ----
  for (int idx = tid * 4; idx < LDSF; idx += NT * 4)
    *(float4*)(sh + idx) = make_float4(0.f, 0.f, 0.f, 0.f);
  __syncthreads();
  if (tid == 0) sh[tab[SL - 1]] = red[20];
  __syncthreads();

  // ---- outside: width pairs descending, then singles ----
  outsideP<32>(254, 240, tid, sc, g, Eg, ETg, sh, tab, E1);
  outsideP<16>(238, 208, tid, sc, g, Eg, ETg, sh, tab, E1);
  outsideP<8>(206, 144, tid, sc, g, Eg, ETg, sh, tab, E1);
  outsideP<4>(142, 16, tid, sc, g, Eg, ETg, sh, tab, E1);
  outsideB<4>(14, 1, tid, sc, g, Eg, ETg, sh, tab);
}

// ---------------- fallback: v2 global-memory kernel (proven) ----------------
__device__ __forceinline__ float grpMaxR(float v, int G) {
#pragma unroll
  for (int o = 32; o; o >>= 1)
    if (o < G) v = fmaxf(v, __shfl_xor(v, o, 64));
  return v;
}
__device__ __forceinline__ float grpSumR(float v, int G) {
#pragma unroll
  for (int o = 32; o; o >>= 1)
    if (o < G) v += __shfl_xor(v, o, 64);
  return v;
}

__global__ __launch_bounds__(NT) void cyk_io_fb(
    const float* __restrict__ scores, float* __restrict__ out,
    float* __restrict__ ws) {
  const int b = blockIdx.x;
  const int tid = threadIdx.x;
  const size_t P = (size_t)SL * SL;
  const float* sc = scores + (size_t)b * P;
  float* g = out + (size_t)b * P;
  float* s = ws + (size_t)b * P;
  float* l = ws + (size_t)(BATCH + b) * P;

  for (int i = tid; i < SL - 1; i += NT) {
    s[i * SL + i + 1] = sc[i * SL + i + 1];
    l[i * SL + i + 1] = 0.f;
  }
  __syncthreads();

  for (int w = 2; w < SL; ++w) {
    const int cells = SL - w;
    int G = NT / cells;
    G = (G >= 64) ? 64 : (1 << (31 - __clz(G)));
    const int lg = 31 - __clz(G);
    const int c = tid >> lg;
    const int lig = tid & (G - 1);
    if (c < cells) {
      const int i = c, j = i + w;
      const float* srow = s + i * SL;
      float m = -INFINITY;
      for (int k = i + 1 + lig; k < j; k += G)
        m = fmaxf(m, srow[k] + s[k * SL + j]);
      m = grpMaxR(m, G);
      float sum = 0.f;
      for (int k = i + 1 + lig; k < j; k += G)
        sum += __expf(srow[k] + s[k * SL + j] - m);
      sum = grpSumR(sum, G);
      if (lig == 0) {
        const float lse = m + __logf(sum);
        s[i * SL + j] = sc[i * SL + j] + lse;
        l[i * SL + j] = lse;
      }
    }
    __syncthreads();
  }

  if (tid == 0) g[0 * SL + (SL - 1)] = 1.0f;
  __syncthreads();

  for (int w = SL - 2; w >= 1; --w) {
    const int cells = SL - w;
    int G = NT / cells;
    G = (G >= 64) ? 64 : (1 << (31 - __clz(G)));
    const int lg = 31 - __clz(G);
    const int c = tid >> lg;
    const int lig = tid & (G - 1);
    if (c < cells) {
      const int p = c, q = p + w;
      const float spq = s[p * SL + q];
      const int TR = SL - 1 - q;
      const int T = TR + p;
      float acc = 0.f;
      for (int t = lig; t < T; t += G) {
        if (t < TR) {
          const int j = q + 1 + t;
          acc += g[p * SL + j] * __expf(spq + s[q * SL + j] - l[p * SL + j]);
        } else {
          const int i = t - TR;
          acc += g[i * SL + q] * __expf(s[i * SL + p] + spq - l[i * SL + q]);
        }
      }
      acc = grpSumR(acc, G);
      if (lig == 0) g[p * SL + q] = acc;
    }
    __syncthreads();
  }
}

extern "C" void kernel_launch(void* const* d_in, const int* in_sizes, int n_in,
                              void* d_out, int out_size, void* d_ws, size_t ws_size,
                              hipStream_t stream) {
  const float* scores = (const float*)d_in[0];
  // d_in[1] = mask: triu(k=1) broadcast -> lens == SL-1 always; unused.
  float* out = (float*)d_out;
  float* ws = (float*)d_ws;

  const size_t sq = (size_t)SL * SL * sizeof(float);       // 256 KB
  hipMemsetAsync(d_out, 0, (size_t)BATCH * sq, stream);

  int dev = 0;
  hipGetDevice(&dev);
  int maxShm = 0;
  hipDeviceGetAttribute(&maxShm, hipDeviceAttributeMaxSharedMemoryPerBlock, dev);
  (void)hipFuncSetAttribute(reinterpret_cast<const void*>(cyk_pair),
                            hipFuncAttributeMaxDynamicSharedMemorySize, LDSB);

  if (maxShm >= LDSB && ws_size >= (size_t)2 * BATCH * sq) {
    hipMemsetAsync(ws, 0, (size_t)2 * BATCH * sq, stream);  // Eg/ETg guards = 0
    cyk_pair<<<BATCH, NT, LDSB, stream>>>(scores, out, ws);
  } else {
    cyk_io_fb<<<BATCH, NT, 0, stream>>>(scores, out, ws);
  }
}

// Round 5
// 653.686 us; speedup vs baseline: 3.3375x; 1.0767x over previous
//
#include <hip/hip_runtime.h>

#define SL 256
#define BATCH 8
#define NT 1024
#define W0 16
#define LDSF 33152                    // packed triangle (floats), 16B-aligned rows
#define TABN 264                      // 256 + zero pad for gather tails
#define LDSB ((LDSF + 32 + TABN + 3 * 256) * 4)   // red + tab + Es1/Es2/Es3 = 136,864 B

// Row j (j in [1,255], holding cells (k,j), k=0..j-1) packed: rows j and 256-j
// share a 260-float slot; every row base is 16B-aligned.
__device__ __forceinline__ int rowOff(int j) {
  int jp = (j > 128) ? (256 - j) : j;
  int base = (jp - 1) * 260;
  if (j > 128) base += (jp + 3) & ~3;
  return base;
}

template <int G>
__device__ __forceinline__ float grpSum(float v) {
#pragma unroll
  for (int o = G >> 1; o; o >>= 1) v += __shfl_xor(v, o, 64);
  return v;
}

// Raw barrier draining only LDS ops: global stores (g output) float across it.
__device__ __forceinline__ void barrier_lgkm() {
  __builtin_amdgcn_sched_barrier(0);
  asm volatile("s_waitcnt lgkmcnt(0)" ::: "memory");
  __builtin_amdgcn_s_barrier();
  __builtin_amdgcn_sched_barrier(0);
}

// Rescale LDS E triangle (+Es1/2/3 copies) by exp(-dc*width) for widths <= wcur.
__device__ void rescaleE(int tid, float dc, int wcur, float* sh,
                         float* Es1, float* Es2, float* Es3,
                         const int* __restrict__ tab) {
  const int lane = tid & 63, wave = tid >> 6;
  for (int j = 1 + wave; j < SL; j += 16) {
    int jlo = j - wcur; if (jlo < 0) jlo = 0;
    int base = tab[j];
    for (int i = jlo + lane; i < j; i += 64)
      sh[base + i] *= __expf(-dc * (float)(j - i));
  }
  const float f1 = __expf(-dc);
  const float f2 = f1 * f1;
  const float f3 = f2 * f1;
  for (int x = tid; x < SL; x += NT) {
    Es1[x] *= f1; Es2[x] *= f2; Es3[x] *= f3;
  }
}

// ---- paired inside (proven): one barrier computes widths (w, w+1) ----
template <int G>
__device__ void insideP(int wlo, int whi, int t0, int tid,
                        const float* __restrict__ sc, float* __restrict__ sh,
                        float* __restrict__ red, const int* __restrict__ tab,
                        float* __restrict__ Es1, float* __restrict__ Es2,
                        float* __restrict__ Es3) {
  constexpr int LG = (G == 4) ? 2 : (G == 8) ? 3 : (G == 16) ? 4 : 5;
  constexpr int NG = 64 / G;
  const int lane = tid & 63, wv = tid >> 6;
  const int l = lane >> LG, lig = lane & (G - 1);
  const int i = wv * (NG - 1) + l;
  for (int w = wlo; w <= whi; w += 2) {
    const int t = t0 + ((w - wlo) >> 1);
    const float fl = red[16 + ((t - 1) & 1)];
    const unsigned wm1 = (unsigned)(w - 1);
    const unsigned wm2 = (unsigned)(w - 2);
    const bool vw = i < SL - w;
    const bool vw1 = (l < NG - 1) && (i < SL - w - 1);
    const int jw = (i + w < SL) ? i + w : SL - 1;
    const int jw1 = (i + w + 1 < SL) ? i + w + 1 : SL - 1;
    const int ojw = tab[jw], ojw1 = tab[jw1];
    const float scw = sc[i * SL + jw];
    const float scw1 = sc[i * SL + jw1];
    float a0 = 0.f, a1 = 0.f, b0 = 0.f, b1 = 0.f;
    if (vw) {
      for (int s4 = ((i + 1) & ~3) + 4 * lig; s4 < i + w; s4 += 4 * G) {
        float4 rw = *(const float4*)(sh + ojw + s4);
        float4 rw1 = *(const float4*)(sh + ojw1 + s4);
        int4 tv = *(const int4*)(tab + s4);
        float e0 = sh[tv.x + i], e1 = sh[tv.y + i];
        float e2 = sh[tv.z + i], e3 = sh[tv.w + i];
        const int d0 = s4 - i;
        float f0 = ((unsigned)(d0 - 1) < wm1) ? e0 : 0.f;
        float f1 = ((unsigned)(d0    ) < wm1) ? e1 : 0.f;
        float f2 = ((unsigned)(d0 + 1) < wm1) ? e2 : 0.f;
        float f3 = ((unsigned)(d0 + 2) < wm1) ? e3 : 0.f;
        a0 = fmaf(f0, rw.x, a0); a1 = fmaf(f1, rw.y, a1);
        a0 = fmaf(f2, rw.z, a0); a1 = fmaf(f3, rw.w, a1);
        float g0 = ((unsigned)(d0 - 2) < wm2) ? e0 : 0.f;
        float g1 = ((unsigned)(d0 - 1) < wm2) ? e1 : 0.f;
        float g2 = ((unsigned)(d0    ) < wm2) ? e2 : 0.f;
        float g3 = ((unsigned)(d0 + 1) < wm2) ? e3 : 0.f;
        b0 = fmaf(g0, rw1.x, b0); b1 = fmaf(g1, rw1.y, b1);
        b0 = fmaf(g2, rw1.z, b0); b1 = fmaf(g3, rw1.w, b1);
      }
    }
    float accw = grpSum<G>(a0 + a1);
    float accw1 = grpSum<G>(b0 + b1);
    float Ew = __expf(scw) * accw;
    if (vw && lig == 0) {
      sh[ojw + i] = Ew;
      if (accw > 3.5e19f || accw < 3e-16f) red[16 + (t & 1)] = fmaxf(accw, 1e-30f);
    }
    float EwN = __shfl_down(Ew, G, 64);
    if (vw1) {
      float tot = accw1 + Es1[i] * EwN + Ew * Es1[jw];
      if (lig == 0) {
        sh[ojw1 + i] = __expf(scw1) * tot;
        if (tot > 3.5e19f || tot < 3e-16f) red[16 + (t & 1)] = fmaxf(tot, 1e-30f);
      }
    }
    __syncthreads();
    if (fl != 0.f) {
      float dc = (__logf(fl) + 8.0f) / (float)(w - 2);
      rescaleE(tid, dc, w + 1, sh, Es1, Es2, Es3, tab);
      __syncthreads();
      if (tid == 0) { red[16] = 0.f; red[17] = 0.f; }
      __syncthreads();
    }
  }
}

// ---- quad inside: one barrier computes widths (w..w+3) ----
// Mapping stride NG-3 (3-row overlap) so fixup neighbors i+1..i+3 are in-wave.
// All bulk masks two-sided; duplicated boundary rows write identical values.
template <int G>
__device__ void insideQ(int wlo, int whi, int t0, int tid,
                        const float* __restrict__ sc, float* __restrict__ sh,
                        float* __restrict__ red, const int* __restrict__ tab,
                        float* __restrict__ Es1, float* __restrict__ Es2,
                        float* __restrict__ Es3) {
  constexpr int LG = (G == 4) ? 2 : 3;
  constexpr int NG = 64 / G;
  const int lane = tid & 63, wv = tid >> 6;
  const int l = lane >> LG, lig = lane & (G - 1);
  const int i = wv * (NG - 3) + l;
  for (int w = wlo; w <= whi; w += 4) {
    const int t = t0 + ((w - wlo) >> 2);
    const float fl = red[16 + ((t - 1) & 1)];
    const bool v0 = i < SL - w;
    const bool v1 = i < SL - w - 1;
    const bool v2 = i < SL - w - 2;
    const bool v3 = i < SL - w - 3;
    const int j0 = (i + w < SL) ? i + w : SL - 1;
    const int j1 = (i + w + 1 < SL) ? i + w + 1 : SL - 1;
    const int j2 = (i + w + 2 < SL) ? i + w + 2 : SL - 1;
    const int j3 = (i + w + 3 < SL) ? i + w + 3 : SL - 1;
    const int o0 = tab[j0], o1 = tab[j1], o2 = tab[j2], o3 = tab[j3];
    const int rb = i * SL;
    const float s0 = sc[rb + j0], s1 = sc[rb + j1];
    const float s2 = sc[rb + j2], s3 = sc[rb + j3];
    float a0=0.f,a1=0.f,b0=0.f,b1=0.f,c0=0.f,c1=0.f,e4a=0.f,e4b=0.f;
    if (v0) {
      const unsigned mA = (unsigned)(w - 1);   // m=0: k-i in [1, w-1]
      const unsigned mB = (unsigned)(w - 2);   // m=1: k-i in [2, w-1]
      const unsigned mC = (unsigned)(w - 3);   // m=2: k-i in [3, w-1]
      const unsigned mD = (unsigned)(w - 4);   // m=3: k-i in [4, w-1]
      for (int s4 = ((i + 1) & ~3) + 4 * lig; s4 < i + w; s4 += 4 * G) {
        float4 r0 = *(const float4*)(sh + o0 + s4);
        float4 r1 = *(const float4*)(sh + o1 + s4);
        float4 r2 = *(const float4*)(sh + o2 + s4);
        float4 r3 = *(const float4*)(sh + o3 + s4);
        int4 tv = *(const int4*)(tab + s4);
        float e0 = sh[tv.x + i], e1 = sh[tv.y + i];
        float e2 = sh[tv.z + i], e3 = sh[tv.w + i];
        const int dd = s4 - i;
        float f0 = ((unsigned)(dd - 1) < mA) ? e0 : 0.f;
        float f1 = ((unsigned)(dd    ) < mA) ? e1 : 0.f;
        float f2 = ((unsigned)(dd + 1) < mA) ? e2 : 0.f;
        float f3 = ((unsigned)(dd + 2) < mA) ? e3 : 0.f;
        a0 = fmaf(f0, r0.x, a0); a1 = fmaf(f1, r0.y, a1);
        a0 = fmaf(f2, r0.z, a0); a1 = fmaf(f3, r0.w, a1);
        float g0 = ((unsigned)(dd - 2) < mB) ? e0 : 0.f;
        float g1 = ((unsigned)(dd - 1) < mB) ? e1 : 0.f;
        float g2 = ((unsigned)(dd    ) < mB) ? e2 : 0.f;
        float g3 = ((unsigned)(dd + 1) < mB) ? e3 : 0.f;
        b0 = fmaf(g0, r1.x, b0); b1 = fmaf(g1, r1.y, b1);
        b0 = fmaf(g2, r1.z, b0); b1 = fmaf(g3, r1.w, b1);
        float h0 = ((unsigned)(dd - 3) < mC) ? e0 : 0.f;
        float h1 = ((unsigned)(dd - 2) < mC) ? e1 : 0.f;
        float h2 = ((unsigned)(dd - 1) < mC) ? e2 : 0.f;
        float h3 = ((unsigned)(dd    ) < mC) ? e3 : 0.f;
        c0 = fmaf(h0, r2.x, c0); c1 = fmaf(h1, r2.y, c1);
        c0 = fmaf(h2, r2.z, c0); c1 = fmaf(h3, r2.w, c1);
        float k0 = ((unsigned)(dd - 4) < mD) ? e0 : 0.f;
        float k1 = ((unsigned)(dd - 3) < mD) ? e1 : 0.f;
        float k2 = ((unsigned)(dd - 2) < mD) ? e2 : 0.f;
        float k3 = ((unsigned)(dd - 1) < mD) ? e3 : 0.f;
        e4a = fmaf(k0, r3.x, e4a); e4b = fmaf(k1, r3.y, e4b);
        e4a = fmaf(k2, r3.z, e4a); e4b = fmaf(k3, r3.w, e4b);
      }
    }
    float A0 = grpSum<G>(a0 + a1);
    float A1 = grpSum<G>(b0 + b1);
    float A2 = grpSum<G>(c0 + c1);
    float A3 = grpSum<G>(e4a + e4b);
    const float es1i = Es1[i], es2i = Es2[i], es3i = Es3[i];
    const float E0 = __expf(s0) * A0;
    const float n10 = __shfl_down(E0, G, 64);
    const float n20 = __shfl_down(E0, 2 * G, 64);
    const float n30 = __shfl_down(E0, 3 * G, 64);
    const float T1 = A1 + es1i * n10 + E0 * Es1[j0];
    const float E1v = __expf(s1) * T1;
    const float n11 = __shfl_down(E1v, G, 64);
    const float n21 = __shfl_down(E1v, 2 * G, 64);
    const float T2 = A2 + es1i * n11 + E1v * Es1[j1] + es2i * n20 + E0 * Es2[j0];
    const float E2v = __expf(s2) * T2;
    const float n12 = __shfl_down(E2v, G, 64);
    const float T3 = A3 + es1i * n12 + E2v * Es1[j2] + es2i * n21 + E1v * Es2[j1]
                        + es3i * n30 + E0 * Es3[j0];
    const float E3v = __expf(s3) * T3;
    if (lig == 0) {
      if (v0)                sh[o0 + i] = E0;
      if (v1 && l <= NG - 2) sh[o1 + i] = E1v;
      if (v2 && l <= NG - 3) sh[o2 + i] = E2v;
      if (v3 && l <= NG - 4) sh[o3 + i] = E3v;
      if (v0 && (A0 > 3.5e19f || A0 < 3e-16f)) red[16 + (t & 1)] = fmaxf(A0, 1e-30f);
      if (v3 && l <= NG - 4 && (T3 > 3.5e19f || T3 < 3e-16f))
        red[16 + (t & 1)] = fmaxf(T3, 1e-30f);
    }
    __syncthreads();
    if (fl != 0.f) {
      float dc = (__logf(fl) + 8.0f) / (float)(w - 3);
      rescaleE(tid, dc, w + 3, sh, Es1, Es2, Es3, tab);
      __syncthreads();
      if (tid == 0) { red[16] = 0.f; red[17] = 0.f; }
      __syncthreads();
    }
  }
}

// ---- paired outside (proven): widths (wA, wA-1) descending ----
template <int G>
__device__ void outsideP(int wAhi, int wAlo, int tid, const float* __restrict__ sc,
                         float* __restrict__ gOut, const float* __restrict__ Eg,
                         const float* __restrict__ ETg, float* __restrict__ shH,
                         const int* __restrict__ tab, const float* __restrict__ Es1) {
  constexpr int LG = (G == 4) ? 2 : (G == 8) ? 3 : (G == 16) ? 4 : 5;
  constexpr int NG = 64 / G;
  const int lane = tid & 63, wv = tid >> 6;
  const int l = lane >> LG, lig = lane & (G - 1);
  const int p = wv * (NG - 1) + l;
  for (int wA = wAhi; wA >= wAlo; wA -= 2) {
    const int wB = wA - 1;
    const bool vA = p < SL - wA;
    const bool vB = (l >= 1 || wv == 0) && (p < SL - wB);
    const int qA = p + wA, qB = p + wB;
    const int qAc = (qA < SL) ? qA : SL - 1;
    const int qBc = (qB < SL) ? qB : SL - 1;
    const int oA = tab[qAc], oB = tab[qBc];
    const float scA = sc[p * SL + qAc];
    const float scB = sc[p * SL + qBc];
    float EpA = 0.f, EpB = 0.f;
    if (lig == 0) {
      if (vA) EpA = Eg[p * SL + qA];
      if (vB) EpB = Eg[p * SL + qB];
    }
    float a0 = 0.f, a1 = 0.f, b0 = 0.f, b1 = 0.f;
    if (vA || vB) {
      const float* erA = Eg + (size_t)qAc * SL;
      const float* erB = Eg + (size_t)qBc * SL;
      for (int s4 = ((qA + 1) & ~3) + 4 * lig; s4 < SL; s4 += 4 * G) {
        float4 eA = *(const float4*)(erA + s4);
        float4 eB = *(const float4*)(erB + s4);
        int4 tv = *(const int4*)(tab + s4);
        float h0 = shH[tv.x + p], h1 = shH[tv.y + p];
        float h2 = shH[tv.z + p], h3 = shH[tv.w + p];
        float m0 = (s4 + 0 > qA) ? h0 : 0.f, m1 = (s4 + 1 > qA) ? h1 : 0.f;
        float m2 = (s4 + 2 > qA) ? h2 : 0.f, m3 = (s4 + 3 > qA) ? h3 : 0.f;
        a0 = fmaf(eA.x, m0, a0); a1 = fmaf(eA.y, m1, a1);
        a0 = fmaf(eA.z, m2, a0); a1 = fmaf(eA.w, m3, a1);
        b0 = fmaf(eB.x, m0, b0); b1 = fmaf(eB.y, m1, b1);
        b0 = fmaf(eB.z, m2, b0); b1 = fmaf(eB.w, m3, b1);
      }
      for (int s4 = 4 * lig; s4 < p; s4 += 4 * G) {
        float4 ev = *(const float4*)(ETg + (size_t)p * SL + s4);
        float4 hA = *(const float4*)(shH + oA + s4);
        float4 hB = *(const float4*)(shH + oB + s4);
        a0 = fmaf(ev.x, hA.x, a0); a1 = fmaf(ev.y, hA.y, a1);
        a0 = fmaf(ev.z, hA.z, a0); a1 = fmaf(ev.w, hA.w, a1);
        float n0 = (s4 + 0 < p - 1) ? hB.x : 0.f;
        float n1 = (s4 + 1 < p - 1) ? hB.y : 0.f;
        float n2 = (s4 + 2 < p - 1) ? hB.z : 0.f;
        float n3 = (s4 + 3 < p - 1) ? hB.w : 0.f;
        b0 = fmaf(ev.x, n0, b0); b1 = fmaf(ev.y, n1, b1);
        b0 = fmaf(ev.z, n2, b0); b1 = fmaf(ev.w, n3, b1);
      }
    }
    float accA = grpSum<G>(a0 + a1);
    float accBb = grpSum<G>(b0 + b1);
    float HA = __expf(scA) * accA;
    if (vA && lig == 0) {
      shH[oA + p] = HA;
      gOut[p * SL + qA] = EpA * accA;
    }
    float HAup = __shfl_up(HA, G, 64);
    if (vB) {
      float accB = accBb + (vA ? Es1[qBc] * HA : 0.f)
                         + ((p > 0) ? Es1[p - 1] * HAup : 0.f);
      if (lig == 0) {
        shH[oB + p] = __expf(scB) * accB;
        gOut[p * SL + qB] = EpB * accB;
      }
    }
    barrier_lgkm();
  }
}

// ---- quad outside: widths (wA..wA-3) descending in one barrier ----
template <int G>
__device__ void outsideQ(int wAhi, int wAlo, int tid, const float* __restrict__ sc,
                         float* __restrict__ gOut, const float* __restrict__ Eg,
                         const float* __restrict__ ETg, float* __restrict__ shH,
                         const int* __restrict__ tab, const float* __restrict__ Es1,
                         const float* __restrict__ Es2, const float* __restrict__ Es3) {
  constexpr int LG = (G == 4) ? 2 : 3;
  constexpr int NG = 64 / G;
  const int lane = tid & 63, wv = tid >> 6;
  const int l = lane >> LG, lig = lane & (G - 1);
  const int p = wv * (NG - 3) + l;
  for (int wA = wAhi; wA >= wAlo; wA -= 4) {
    const bool v0 = p < SL - wA;
    const bool v1 = p < SL - wA + 1;
    const bool v2 = p < SL - wA + 2;
    const bool v3 = p < SL - wA + 3;
    const int q0 = p + wA, q1 = q0 - 1, q2 = q0 - 2, q3 = q0 - 3;
    const int qc0 = (q0 < SL) ? q0 : SL - 1;
    const int qc1 = (q1 < SL) ? q1 : SL - 1;
    const int qc2 = (q2 < SL) ? q2 : SL - 1;
    const int qc3 = (q3 < SL) ? q3 : SL - 1;
    const int o0 = tab[qc0], o1 = tab[qc1], o2 = tab[qc2], o3 = tab[qc3];
    const int rb = p * SL;
    const float s0 = sc[rb + qc0], s1 = sc[rb + qc1];
    const float s2 = sc[rb + qc2], s3 = sc[rb + qc3];
    float Ep0 = 0.f, Ep1 = 0.f, Ep2 = 0.f, Ep3 = 0.f;
    if (lig == 0) {
      if (v0) Ep0 = Eg[rb + q0];
      if (v1) Ep1 = Eg[rb + q1];
      if (v2) Ep2 = Eg[rb + q2];
      if (v3) Ep3 = Eg[rb + q3];
    }
    float a0=0.f,a1=0.f,b0=0.f,b1=0.f,c0=0.f,c1=0.f,e4a=0.f,e4b=0.f;
    if (v3) {
      const float* er0 = Eg + (size_t)qc0 * SL;
      const float* er1 = Eg + (size_t)qc1 * SL;
      const float* er2 = Eg + (size_t)qc2 * SL;
      const float* er3 = Eg + (size_t)qc3 * SL;
      for (int s4 = ((q0 + 1) & ~3) + 4 * lig; s4 < SL; s4 += 4 * G) {
        float4 e0v = *(const float4*)(er0 + s4);
        float4 e1v = *(const float4*)(er1 + s4);
        float4 e2v = *(const float4*)(er2 + s4);
        float4 e3v = *(const float4*)(er3 + s4);
        int4 tv = *(const int4*)(tab + s4);
        float h0 = (s4 + 0 > q0) ? shH[tv.x + p] : 0.f;
        float h1 = (s4 + 1 > q0) ? shH[tv.y + p] : 0.f;
        float h2 = (s4 + 2 > q0) ? shH[tv.z + p] : 0.f;
        float h3 = (s4 + 3 > q0) ? shH[tv.w + p] : 0.f;
        a0 = fmaf(e0v.x, h0, a0); a1 = fmaf(e0v.y, h1, a1);
        a0 = fmaf(e0v.z, h2, a0); a1 = fmaf(e0v.w, h3, a1);
        b0 = fmaf(e1v.x, h0, b0); b1 = fmaf(e1v.y, h1, b1);
        b0 = fmaf(e1v.z, h2, b0); b1 = fmaf(e1v.w, h3, b1);
        c0 = fmaf(e2v.x, h0, c0); c1 = fmaf(e2v.y, h1, c1);
        c0 = fmaf(e2v.z, h2, c0); c1 = fmaf(e2v.w, h3, c1);
        e4a = fmaf(e3v.x, h0, e4a); e4b = fmaf(e3v.y, h1, e4b);
        e4a = fmaf(e3v.z, h2, e4a); e4b = fmaf(e3v.w, h3, e4b);
      }
      for (int s4 = 4 * lig; s4 < p; s4 += 4 * G) {
        float4 ev = *(const float4*)(ETg + (size_t)p * SL + s4);
        float4 h0v = *(const float4*)(shH + o0 + s4);
        float4 h1v = *(const float4*)(shH + o1 + s4);
        float4 h2v = *(const float4*)(shH + o2 + s4);
        float4 h3v = *(const float4*)(shH + o3 + s4);
        a0 = fmaf(ev.x, h0v.x, a0); a1 = fmaf(ev.y, h0v.y, a1);
        a0 = fmaf(ev.z, h0v.z, a0); a1 = fmaf(ev.w, h0v.w, a1);
        float n0 = (s4 + 0 < p - 1) ? h1v.x : 0.f;
        float n1 = (s4 + 1 < p - 1) ? h1v.y : 0.f;
        float n2 = (s4 + 2 < p - 1) ? h1v.z : 0.f;
        float n3 = (s4 + 3 < p - 1) ? h1v.w : 0.f;
        b0 = fmaf(ev.x, n0, b0); b1 = fmaf(ev.y, n1, b1);
        b0 = fmaf(ev.z, n2, b0); b1 = fmaf(ev.w, n3, b1);
        float x0 = (s4 + 0 < p - 2) ? h2v.x : 0.f;
        float x1 = (s4 + 1 < p - 2) ? h2v.y : 0.f;
        float x2 = (s4 + 2 < p - 2) ? h2v.z : 0.f;
        float x3 = (s4 + 3 < p - 2) ? h2v.w : 0.f;
        c0 = fmaf(ev.x, x0, c0); c1 = fmaf(ev.y, x1, c1);
        c0 = fmaf(ev.z, x2, c0); c1 = fmaf(ev.w, x3, c1);
        float y0 = (s4 + 0 < p - 3) ? h3v.x : 0.f;
        float y1 = (s4 + 1 < p - 3) ? h3v.y : 0.f;
        float y2 = (s4 + 2 < p - 3) ? h3v.z : 0.f;
        float y3 = (s4 + 3 < p - 3) ? h3v.w : 0.f;
        e4a = fmaf(ev.x, y0, e4a); e4b = fmaf(ev.y, y1, e4b);
        e4a = fmaf(ev.z, y2, e4a); e4b = fmaf(ev.w, y3, e4b);
      }
    }
    float A0 = grpSum<G>(a0 + a1);
    float A1 = grpSum<G>(b0 + b1);
    float A2 = grpSum<G>(c0 + c1);
    float A3 = grpSum<G>(e4a + e4b);
    const float ep1 = (p >= 1) ? Es1[p - 1] : 0.f;
    const float ep2 = (p >= 2) ? Es2[p - 2] : 0.f;
    const float ep3 = (p >= 3) ? Es3[p - 3] : 0.f;
    const float H0 = __expf(s0) * A0;
    const float u10 = __shfl_up(H0, G, 64);
    const float u20 = __shfl_up(H0, 2 * G, 64);
    const float u30 = __shfl_up(H0, 3 * G, 64);
    const float T1 = A1 + (v0 ? Es1[qc1] * H0 : 0.f) + ep1 * u10;
    const float H1 = __expf(s1) * T1;
    const float u11 = __shfl_up(H1, G, 64);
    const float u21 = __shfl_up(H1, 2 * G, 64);
    const float T2 = A2 + (v1 ? Es1[qc2] * H1 : 0.f) + ep1 * u11
                        + (v0 ? Es2[qc2] * H0 : 0.f) + ep2 * u20;
    const float H2 = __expf(s2) * T2;
    const float u12 = __shfl_up(H2, G, 64);
    const float T3 = A3 + (v2 ? Es1[qc3] * H2 : 0.f) + ep1 * u12
                        + (v1 ? Es2[qc3] * H1 : 0.f) + ep2 * u21
                        + (v0 ? Es3[qc3] * H0 : 0.f) + ep3 * u30;
    const float H3 = __expf(s3) * T3;
    const bool okl1 = (l >= 1) || (wv == 0);
    const bool okl2 = (l >= 2) || (wv == 0);
    const bool okl3 = (l >= 3) || (wv == 0);
    if (lig == 0) {
      if (v0)         { shH[o0 + p] = H0; gOut[rb + q0] = Ep0 * A0; }
      if (v1 && okl1) { shH[o1 + p] = H1; gOut[rb + q1] = Ep1 * T1; }
      if (v2 && okl2) { shH[o2 + p] = H2; gOut[rb + q2] = Ep2 * T2; }
      if (v3 && okl3) { shH[o3 + p] = H3; gOut[rb + q3] = Ep3 * T3; }
    }
    barrier_lgkm();
  }
}

// ---- unpaired outside (proven round-1 shape) for small widths ----
template <int G>
__device__ void outsideB(int w0, int w1, int tid,
    const float* __restrict__ sc, float* __restrict__ gOut,
    const float* __restrict__ Eg, const float* __restrict__ ETg,
    float* __restrict__ shH, const int* __restrict__ tab) {
  constexpr int LG = (G == 4) ? 2 : (G == 8) ? 3 : (G == 16) ? 4 : (G == 32) ? 5 : 6;
  const int c = tid >> LG, lig = tid & (G - 1);
  for (int w = w0; w >= w1; --w) {
    if (c < SL - w) {
      const int p = c, q = p + w;
      float scv = 0.f, Epq = 0.f;
      if (lig == 0) { scv = sc[p * SL + q]; Epq = Eg[p * SL + q]; }
      float a0 = 0.f, a1 = 0.f;
      const float* er = Eg + (size_t)q * SL;
      for (int s4 = ((q + 1) & ~3) + 4 * lig; s4 < SL; s4 += 4 * G) {
        float4 ev = *(const float4*)(er + s4);
        int4 tv = *(const int4*)(tab + s4);
        float h0 = shH[tv.x + p], h1 = shH[tv.y + p];
        float h2 = shH[tv.z + p], h3 = shH[tv.w + p];
        a0 = fmaf(ev.x, (s4 + 0 > q) ? h0 : 0.f, a0);
        a1 = fmaf(ev.y, (s4 + 1 > q) ? h1 : 0.f, a1);
        a0 = fmaf(ev.z, (s4 + 2 > q) ? h2 : 0.f, a0);
        a1 = fmaf(ev.w, (s4 + 3 > q) ? h3 : 0.f, a1);
      }
      if (p > 0) {
        const float* et = ETg + (size_t)p * SL;
        const float* hq = shH + tab[q];
        for (int s4 = 4 * lig; s4 < p; s4 += 4 * G) {
          float4 ev = *(const float4*)(et + s4);
          float4 hv = *(const float4*)(hq + s4);
          a0 = fmaf(ev.x, hv.x, a0);
          a1 = fmaf(ev.y, hv.y, a1);
          a0 = fmaf(ev.z, hv.z, a0);
          a1 = fmaf(ev.w, hv.w, a1);
        }
      }
      float acc = grpSum<G>(a0 + a1);
      if (lig == 0) {
        gOut[p * SL + q] = Epq * acc;
        shH[tab[q] + p] = acc * __expf(scv);
      }
    }
    barrier_lgkm();
  }
}

__global__ __launch_bounds__(NT) void cyk_quad(
    const float* __restrict__ scores, float* __restrict__ out,
    float* __restrict__ ws) {
  extern __shared__ float sh[];
  float* red = sh + LDSF;
  int* tab = (int*)(sh + LDSF + 32);
  float* Es1 = sh + LDSF + 32 + TABN;
  float* Es2 = Es1 + 256;
  float* Es3 = Es2 + 256;
  const int b = blockIdx.x;
  const int tid = threadIdx.x;
  const int lane = tid & 63;
  const int wave = tid >> 6;
  const size_t P = (size_t)SL * SL;
  const float* sc = scores + (size_t)b * P;
  float* g   = out + (size_t)b * P;
  float* Eg  = ws + (size_t)b * P;                 // E row-major (read-only after dump)
  float* ETg = ws + (size_t)(BATCH + b) * P;       // E col-major (read-only after dump)

  for (int idx = tid * 4; idx < LDSF; idx += NT * 4)
    *(float4*)(sh + idx) = make_float4(0.f, 0.f, 0.f, 0.f);
  if (tid < 32) red[tid] = 0.f;
  if (tid < TABN) tab[tid] = (tid >= 1 && tid <= 255) ? rowOff(tid) : 0;
  if (tid < 256) { Es1[tid] = 0.f; Es2[tid] = 0.f; Es3[tid] = 0.f; }
  __syncthreads();

  // width 1 seeds (log space)
  for (int i = tid; i < SL - 1; i += NT)
    sh[tab[i + 1] + i] = sc[i * SL + i + 1];
  __syncthreads();

  // ---- phase A: widths 2..W0, log space ----
  {
    const int c4 = tid >> 2, lig = tid & 3;
    for (int w = 2; w <= W0; ++w) {
      if (c4 < SL - w) {
        const int i = c4, j = i + w;
        const int oj = tab[j];
        float scv = 0.f;
        if (lig == 0) scv = sc[i * SL + j];
        float m = -1e30f, sum = 0.f;
        for (int k = i + 1 + lig; k < j; k += 4) {
          float t = sh[tab[k] + i] + sh[oj + k];
          float nm = fmaxf(m, t);
          sum = sum * __expf(m - nm) + __expf(t - nm);
          m = nm;
        }
#pragma unroll
        for (int o = 2; o; o >>= 1) {
          float mo = __shfl_xor(m, o, 64);
          float so = __shfl_xor(sum, o, 64);
          float nm = fmaxf(m, mo);
          sum = sum * __expf(m - nm) + so * __expf(mo - nm);
          m = nm;
        }
        if (lig == 0) sh[oj + i] = scv + m + __logf(sum);
      }
      __syncthreads();
    }
  }

  // ---- calibrate cc = max(s at width W0)/W0 ----
  {
    int idx = tid < SL - W0 ? tid : SL - W0 - 1;
    float v = sh[tab[idx + W0] + idx];
#pragma unroll
    for (int o = 32; o; o >>= 1) v = fmaxf(v, __shfl_xor(v, o, 64));
    if (lane == 0) red[wave] = v;
  }
  __syncthreads();
  float cc;
  {
    float mx = red[0];
#pragma unroll
    for (int t = 1; t < 16; ++t) mx = fmaxf(mx, red[t]);
    cc = mx / (float)W0;
  }

  // ---- convert widths 1..W0 to E-space; fill Es1/Es2/Es3 ----
  for (int w = 1; w <= W0; ++w) {
    for (int i = tid; i < SL - w; i += NT) {
      int o = tab[i + w] + i;
      float E = __expf(sh[o] - cc * (float)w);
      sh[o] = E;
      if (w == 1) Es1[i] = E;
      if (w == 2) Es2[i] = E;
      if (w == 3) Es3[i] = E;
    }
  }
  if (tid == 0) { red[16] = 0.f; red[17] = 0.f; }
  __syncthreads();

  // ---- inside: pairs 17..44, quads 45..252, pair (253,254), single 255 ----
  insideP<4>(17, 43, 1, tid, sc, sh, red, tab, Es1, Es2, Es3);
  insideQ<4>(45, 169, 15, tid, sc, sh, red, tab, Es1, Es2, Es3);
  insideQ<8>(173, 249, 47, tid, sc, sh, red, tab, Es1, Es2, Es3);
  insideP<32>(253, 253, 67, tid, sc, sh, red, tab, Es1, Es2, Es3);

  // ---- width 255 (single cell) ----
  {
    float acc = 0.f;
    if (wave == 0) {
      const int o255 = tab[255];
      for (int k = 1 + lane; k < 255; k += 64)
        acc += sh[tab[k]] * sh[o255 + k];          // E[0,k] * E[k,255]
#pragma unroll
      for (int o = 32; o; o >>= 1) acc += __shfl_xor(acc, o, 64);
      if (lane == 0) sh[o255] = __expf(sc[SL - 1]) * acc;
    }
    __syncthreads();
  }

  // ---- dump E -> Eg (row-major) + ETg (col-major); root ----
  for (int idx = tid; idx < SL * SL; idx += NT) {
    int j = idx >> 8, i = idx & 255;
    if (i < j) ETg[idx] = sh[tab[j] + i];
  }
  for (int idx = tid; idx < SL * SL; idx += NT) {
    int i = idx >> 8, k = idx & 255;
    if (k > i) Eg[idx] = sh[tab[k] + i];
  }
  if (tid == 0) {
    float Er = sh[tab[SL - 1]];
    red[20] = (Er > 0.f) ? __expf(sc[SL - 1]) / Er : 0.f;
    g[SL - 1] = 1.0f;
  }
  __syncthreads();                                 // drains vmcnt: E visible

  // ---- re-init LDS triangle as H; seed root ----
  for (int idx = tid * 4; idx < LDSF; idx += NT * 4)
    *(float4*)(sh + idx) = make_float4(0.f, 0.f, 0.f, 0.f);
  __syncthreads();
  if (tid == 0) sh[tab[SL - 1]] = red[20];
  __syncthreads();

  // ---- outside: pair (254,253), quads 252..45, pairs 44..17, singles 16..1 ----
  outsideP<32>(254, 254, tid, sc, g, Eg, ETg, sh, tab, Es1);
  outsideQ<8>(252, 176, tid, sc, g, Eg, ETg, sh, tab, Es1, Es2, Es3);
  outsideQ<4>(172, 48, tid, sc, g, Eg, ETg, sh, tab, Es1, Es2, Es3);
  outsideP<4>(44, 18, tid, sc, g, Eg, ETg, sh, tab, Es1);
  outsideB<4>(16, 1, tid, sc, g, Eg, ETg, sh, tab);
}

// ---------------- fallback: v2 global-memory kernel (proven) ----------------
__device__ __forceinline__ float grpMaxR(float v, int G) {
#pragma unroll
  for (int o = 32; o; o >>= 1)
    if (o < G) v = fmaxf(v, __shfl_xor(v, o, 64));
  return v;
}
__device__ __forceinline__ float grpSumR(float v, int G) {
#pragma unroll
  for (int o = 32; o; o >>= 1)
    if (o < G) v += __shfl_xor(v, o, 64);
  return v;
}

__global__ __launch_bounds__(NT) void cyk_io_fb(
    const float* __restrict__ scores, float* __restrict__ out,
    float* __restrict__ ws) {
  const int b = blockIdx.x;
  const int tid = threadIdx.x;
  const size_t P = (size_t)SL * SL;
  const float* sc = scores + (size_t)b * P;
  float* g = out + (size_t)b * P;
  float* s = ws + (size_t)b * P;
  float* l = ws + (size_t)(BATCH + b) * P;

  for (int i = tid; i < SL - 1; i += NT) {
    s[i * SL + i + 1] = sc[i * SL + i + 1];
    l[i * SL + i + 1] = 0.f;
  }
  __syncthreads();

  for (int w = 2; w < SL; ++w) {
    const int cells = SL - w;
    int G = NT / cells;
    G = (G >= 64) ? 64 : (1 << (31 - __clz(G)));
    const int lg = 31 - __clz(G);
    const int c = tid >> lg;
    const int lig = tid & (G - 1);
    if (c < cells) {
      const int i = c, j = i + w;
      const float* srow = s + i * SL;
      float m = -INFINITY;
      for (int k = i + 1 + lig; k < j; k += G)
        m = fmaxf(m, srow[k] + s[k * SL + j]);
      m = grpMaxR(m, G);
      float sum = 0.f;
      for (int k = i + 1 + lig; k < j; k += G)
        sum += __expf(srow[k] + s[k * SL + j] - m);
      sum = grpSumR(sum, G);
      if (lig == 0) {
        const float lse = m + __logf(sum);
        s[i * SL + j] = sc[i * SL + j] + lse;
        l[i * SL + j] = lse;
      }
    }
    __syncthreads();
  }

  if (tid == 0) g[0 * SL + (SL - 1)] = 1.0f;
  __syncthreads();

  for (int w = SL - 2; w >= 1; --w) {
    const int cells = SL - w;
    int G = NT / cells;
    G = (G >= 64) ? 64 : (1 << (31 - __clz(G)));
    const int lg = 31 - __clz(G);
    const int c = tid >> lg;
    const int lig = tid & (G - 1);
    if (c < cells) {
      const int p = c, q = p + w;
      const float spq = s[p * SL + q];
      const int TR = SL - 1 - q;
      const int T = TR + p;
      float acc = 0.f;
      for (int t = lig; t < T; t += G) {
        if (t < TR) {
          const int j = q + 1 + t;
          acc += g[p * SL + j] * __expf(spq + s[q * SL + j] - l[p * SL + j]);
        } else {
          const int i = t - TR;
          acc += g[i * SL + q] * __expf(s[i * SL + p] + spq - l[i * SL + q]);
        }
      }
      acc = grpSumR(acc, G);
      if (lig == 0) g[p * SL + q] = acc;
    }
    __syncthreads();
  }
}

extern "C" void kernel_launch(void* const* d_in, const int* in_sizes, int n_in,
                              void* d_out, int out_size, void* d_ws, size_t ws_size,
                              hipStream_t stream) {
  const float* scores = (const float*)d_in[0];
  // d_in[1] = mask: triu(k=1) broadcast -> lens == SL-1 always; unused.
  float* out = (float*)d_out;
  float* ws = (float*)d_ws;

  const size_t sq = (size_t)SL * SL * sizeof(float);       // 256 KB
  hipMemsetAsync(d_out, 0, (size_t)BATCH * sq, stream);

  int dev = 0;
  hipGetDevice(&dev);
  int maxShm = 0;
  hipDeviceGetAttribute(&maxShm, hipDeviceAttributeMaxSharedMemoryPerBlock, dev);
  (void)hipFuncSetAttribute(reinterpret_cast<const void*>(cyk_quad),
                            hipFuncAttributeMaxDynamicSharedMemorySize, LDSB);

  if (maxShm >= LDSB && ws_size >= (size_t)2 * BATCH * sq) {
    hipMemsetAsync(ws, 0, (size_t)2 * BATCH * sq, stream);  // Eg/ETg guards = 0
    cyk_quad<<<BATCH, NT, LDSB, stream>>>(scores, out, ws);
  } else {
    cyk_io_fb<<<BATCH, NT, 0, stream>>>(scores, out, ws);
  }
}